// Round 8
// baseline (53.618 us; speedup 1.0000x reference)
//
#include <hip/hip_runtime.h>

#define NPRE 32768
#define NPOST 32768
#define RR 64
#define BATCH 512
#define KSPLIT 128
#define KCHUNK 256  // NPRE / KSPLIT

typedef float f32x4 __attribute__((ext_vector_type(4)));
typedef __bf16 bf16x8 __attribute__((ext_vector_type(8)));
typedef unsigned short u16;
typedef unsigned int u32;

static __device__ __forceinline__ u16 f2bfu(float f) {
  u32 u = __builtin_bit_cast(u32, f);
  return (u16)((u + 0x7fffu + ((u >> 16) & 1u)) >> 16);  // RNE round to bf16
}
static __device__ __forceinline__ __bf16 u2bf(u16 s) {
  return __builtin_bit_cast(__bf16, s);
}
static __device__ __forceinline__ float bf2f(u16 s) {
  return __builtin_bit_cast(float, (u32)s << 16);
}
static __device__ __forceinline__ bf16x8 cvt8(f32x4 lo, f32x4 hi) {
  bf16x8 b;
  b[0] = u2bf(f2bfu(lo.x)); b[1] = u2bf(f2bfu(lo.y));
  b[2] = u2bf(f2bfu(lo.z)); b[3] = u2bf(f2bfu(lo.w));
  b[4] = u2bf(f2bfu(hi.x)); b[5] = u2bf(f2bfu(hi.y));
  b[6] = u2bf(f2bfu(hi.z)); b[7] = u2bf(f2bfu(hi.w));
  return b;
}

// ---- GEMM1 (frozen): zp[kc][b][r] = S[b][kslice] @ V[kslice][r] -----------
__global__ __launch_bounds__(256, 4) void k1(const float* __restrict__ S,
                                             const float* __restrict__ V,
                                             u16* __restrict__ zp) {
  int bid = blockIdx.x;
  int eff = (bid & 7) * 128 + (bid >> 3);  // bijective XCD swizzle (1024 % 8 == 0)
  int grp = eff & 7;
  int kc = eff >> 3;                       // XCD-contiguous kc range
  int lane = threadIdx.x & 63;
  int w = threadIdx.x >> 6;
  int mt = grp * 4 + w;                    // 0..31
  int l15 = lane & 15, g = lane >> 4;
  const float* A = S + (size_t)(mt * 16 + l15) * NPRE + kc * KCHUNK + g * 8;
  const float* Vb = V + (size_t)(kc * KCHUNK + g * 8) * RR + l15;
  f32x4 acc[4] = {};
#pragma unroll 2
  for (int ks = 0; ks < KCHUNK / 32; ++ks) {
    f32x4 a0 = __builtin_nontemporal_load(reinterpret_cast<const f32x4*>(A + ks * 32));
    f32x4 a1 = __builtin_nontemporal_load(reinterpret_cast<const f32x4*>(A + ks * 32 + 4));
    bf16x8 af = cvt8(a0, a1);
    const float* Vk = Vb + (size_t)ks * 32 * RR;
    bf16x8 bfr[4];
#pragma unroll
    for (int t = 0; t < 4; ++t)
#pragma unroll
      for (int j = 0; j < 8; ++j)
        bfr[t][j] = u2bf(f2bfu(Vk[j * RR + t * 16]));  // V[k][r], r = t*16+l15
    acc[0] = __builtin_amdgcn_mfma_f32_16x16x32_bf16(af, bfr[0], acc[0], 0, 0, 0);
    acc[1] = __builtin_amdgcn_mfma_f32_16x16x32_bf16(af, bfr[1], acc[1], 0, 0, 0);
    acc[2] = __builtin_amdgcn_mfma_f32_16x16x32_bf16(af, bfr[2], acc[2], 0, 0, 0);
    acc[3] = __builtin_amdgcn_mfma_f32_16x16x32_bf16(af, bfr[3], acc[3], 0, 0, 0);
  }
  // D layout: col = lane&15 (B-lane space), row = (lane>>4)*4 + reg (A-lane space)
  u16* out = zp + ((size_t)kc * BATCH + mt * 16) * RR;
#pragma unroll
  for (int t = 0; t < 4; ++t)
#pragma unroll
    for (int q = 0; q < 4; ++q)
      out[(g * 4 + q) * RR + t * 16 + l15] = f2bfu(acc[t][q]);
}

// ---- reduce 128 bf16 partials -> z bf16 [BATCH][RR] (frozen) --------------
__global__ __launch_bounds__(1024) void k_red(const u16* __restrict__ zp,
                                              u16* __restrict__ zb) {
  __shared__ float part[4][256];
  int il = threadIdx.x & 255;
  int tg = threadIdx.x >> 8;
  int i = blockIdx.x * 256 + il;
  const u16* p = zp + (size_t)tg * 32 * (BATCH * RR) + i;
  float s0 = 0.f, s1 = 0.f, s2 = 0.f, s3 = 0.f;
#pragma unroll
  for (int t = 0; t < 32; t += 4) {
    s0 += bf2f(p[(size_t)(t + 0) * (BATCH * RR)]);
    s1 += bf2f(p[(size_t)(t + 1) * (BATCH * RR)]);
    s2 += bf2f(p[(size_t)(t + 2) * (BATCH * RR)]);
    s3 += bf2f(p[(size_t)(t + 3) * (BATCH * RR)]);
  }
  part[tg][il] = (s0 + s1) + (s2 + s3);
  __syncthreads();
  if (tg == 0)
    zb[i] = f2bfu((part[0][il] + part[1][il]) + (part[2][il] + part[3][il]));
}

// ---- GEMM2 v4: swapped-operand MFMA + f32x4 stores + 8 waves --------------
// 512 blocks x 512 thr. Block: 512 n x 64 b. U slice staged once in LDS
// (64 KB, XOR-swizzled). Swapped mfma(U_frag, z_frag): D-row space = n, so
// each lane's 4 acc regs = 4 consecutive n -> one f32x4 store per tile
// (1 KB/instruction, 4x fewer stores). 16 waves/CU feed the write stream.
__global__ __launch_bounds__(512) void k2(const u16* __restrict__ zb,
                                          const float* __restrict__ U,
                                          float* __restrict__ y) {
  __shared__ u16 Ub[512 * 64];  // 64 KB, byte = (row*128+col*2)^((row&7)<<4)
  int bid = blockIdx.x;
  int eff = (bid & 7) * 64 + (bid >> 3);  // bijective (512 % 8 == 0)
  int nt = eff >> 3;                      // 8 consecutive n-tiles per XCD
  int bg = eff & 7;
  int n0 = nt * 512;
  int t = threadIdx.x;
  int lane = t & 63;
  int w = t >> 6;                         // 0..7
  int l15 = lane & 15, g = lane >> 4;
  char* Uc = reinterpret_cast<char*>(Ub);

  // stage U slice -> LDS bf16: 32768 floats = 16 iters x 512 thr x 4
#pragma unroll
  for (int i = 0; i < 16; ++i) {
    int f = i * 2048 + t * 4;  // linear float idx within 512x64 slice
    int row = f >> 6;
    int colb = (f & 63) * 2;   // byte col, 8B-aligned
    f32x4 u = *reinterpret_cast<const f32x4*>(U + (size_t)n0 * RR + f);
    uint2 pk;
    pk.x = (u32)f2bfu(u.x) | ((u32)f2bfu(u.y) << 16);
    pk.y = (u32)f2bfu(u.z) | ((u32)f2bfu(u.w) << 16);
    *reinterpret_cast<uint2*>(Uc + ((row * 128 + colb) ^ ((row & 7) << 4))) = pk;
  }
  __syncthreads();

#pragma unroll
  for (int it = 0; it < 4; ++it) {
    int b0 = bg * 64 + it * 16;
    const u16* A = zb + (size_t)(b0 + l15) * RR + g * 8;
    bf16x8 z0 = *reinterpret_cast<const bf16x8*>(A);       // k 0..31 slice
    bf16x8 z1 = *reinterpret_cast<const bf16x8*>(A + 32);  // k 32..63 slice
    f32x4 acc[4] = {};
#pragma unroll
    for (int j = 0; j < 4; ++j) {
      int tau = w + 8 * j;               // n-tile 0..31 within block
      int row = tau * 16 + l15;          // U row (n) 0..511
      int base = row * 128;
      int swz = (row & 7) << 4;
      bf16x8 uA = *reinterpret_cast<const bf16x8*>(Uc + ((base + g * 16) ^ swz));
      bf16x8 uB = *reinterpret_cast<const bf16x8*>(Uc + ((base + 64 + g * 16) ^ swz));
      // swapped: A-operand = U rows (D-row space = n), B-operand = z rows
      acc[j] = __builtin_amdgcn_mfma_f32_16x16x32_bf16(uA, z0, acc[j], 0, 0, 0);
      acc[j] = __builtin_amdgcn_mfma_f32_16x16x32_bf16(uB, z1, acc[j], 0, 0, 0);
    }
    // D: col=l15 <-> b, row=g*4+q <-> n  ->  lane holds 4 consecutive n
    float* yb = y + (size_t)(b0 + l15) * NPOST + n0;
#pragma unroll
    for (int j = 0; j < 4; ++j) {
      int tau = w + 8 * j;
      *reinterpret_cast<f32x4*>(yb + tau * 16 + g * 4) = acc[j];
    }
  }
}

extern "C" void kernel_launch(void* const* d_in, const int* in_sizes, int n_in,
                              void* d_out, int out_size, void* d_ws, size_t ws_size,
                              hipStream_t stream) {
  const float* spikes = (const float*)d_in[0];
  const float* U = (const float*)d_in[1];
  const float* V = (const float*)d_in[2];
  // d_in[3..5]: CSR mask — dead in the reference, unused.
  float* y = (float*)d_out;
  char* ws = (char*)d_ws;
  u16* zp = (u16*)ws;                    // 8 MiB  [KSPLIT][BATCH][RR] bf16
  u16* zb = (u16*)(ws + (8u << 20));     // 64 KiB [BATCH][RR] bf16

  k1<<<1024, 256, 0, stream>>>(spikes, V, zp);
  k_red<<<128, 1024, 0, stream>>>(zp, zb);
  k2<<<512, 512, 0, stream>>>(zb, U, y);
}

// Round 9
// 53.261 us; speedup vs baseline: 1.0067x; 1.0067x over previous
//
#include <hip/hip_runtime.h>

#define NPRE 32768
#define NPOST 32768
#define RR 64
#define BATCH 512
#define KSPLIT 128
#define KCHUNK 256  // NPRE / KSPLIT

typedef float f32x4 __attribute__((ext_vector_type(4)));
typedef __bf16 bf16x8 __attribute__((ext_vector_type(8)));
typedef unsigned short u16;
typedef unsigned int u32;

static __device__ __forceinline__ u16 f2bfu(float f) {
  u32 u = __builtin_bit_cast(u32, f);
  return (u16)((u + 0x7fffu + ((u >> 16) & 1u)) >> 16);  // RNE round to bf16
}
static __device__ __forceinline__ __bf16 u2bf(u16 s) {
  return __builtin_bit_cast(__bf16, s);
}
static __device__ __forceinline__ float bf2f(u16 s) {
  return __builtin_bit_cast(float, (u32)s << 16);
}
static __device__ __forceinline__ bf16x8 cvt8(f32x4 lo, f32x4 hi) {
  bf16x8 b;
  b[0] = u2bf(f2bfu(lo.x)); b[1] = u2bf(f2bfu(lo.y));
  b[2] = u2bf(f2bfu(lo.z)); b[3] = u2bf(f2bfu(lo.w));
  b[4] = u2bf(f2bfu(hi.x)); b[5] = u2bf(f2bfu(hi.y));
  b[6] = u2bf(f2bfu(hi.z)); b[7] = u2bf(f2bfu(hi.w));
  return b;
}

// ---- GEMM1 (frozen): zp[kc][b][r] = S[b][kslice] @ V[kslice][r] -----------
__global__ __launch_bounds__(256, 4) void k1(const float* __restrict__ S,
                                             const float* __restrict__ V,
                                             u16* __restrict__ zp) {
  int bid = blockIdx.x;
  int eff = (bid & 7) * 128 + (bid >> 3);  // bijective XCD swizzle (1024 % 8 == 0)
  int grp = eff & 7;
  int kc = eff >> 3;                       // XCD-contiguous kc range
  int lane = threadIdx.x & 63;
  int w = threadIdx.x >> 6;
  int mt = grp * 4 + w;                    // 0..31
  int l15 = lane & 15, g = lane >> 4;
  const float* A = S + (size_t)(mt * 16 + l15) * NPRE + kc * KCHUNK + g * 8;
  const float* Vb = V + (size_t)(kc * KCHUNK + g * 8) * RR + l15;
  f32x4 acc[4] = {};
#pragma unroll 2
  for (int ks = 0; ks < KCHUNK / 32; ++ks) {
    f32x4 a0 = __builtin_nontemporal_load(reinterpret_cast<const f32x4*>(A + ks * 32));
    f32x4 a1 = __builtin_nontemporal_load(reinterpret_cast<const f32x4*>(A + ks * 32 + 4));
    bf16x8 af = cvt8(a0, a1);
    const float* Vk = Vb + (size_t)ks * 32 * RR;
    bf16x8 bfr[4];
#pragma unroll
    for (int t = 0; t < 4; ++t)
#pragma unroll
      for (int j = 0; j < 8; ++j)
        bfr[t][j] = u2bf(f2bfu(Vk[j * RR + t * 16]));  // V[k][r], r = t*16+l15
    acc[0] = __builtin_amdgcn_mfma_f32_16x16x32_bf16(af, bfr[0], acc[0], 0, 0, 0);
    acc[1] = __builtin_amdgcn_mfma_f32_16x16x32_bf16(af, bfr[1], acc[1], 0, 0, 0);
    acc[2] = __builtin_amdgcn_mfma_f32_16x16x32_bf16(af, bfr[2], acc[2], 0, 0, 0);
    acc[3] = __builtin_amdgcn_mfma_f32_16x16x32_bf16(af, bfr[3], acc[3], 0, 0, 0);
  }
  // D layout: col = lane&15 (B-lane space), row = (lane>>4)*4 + reg (A-lane space)
  u16* out = zp + ((size_t)kc * BATCH + mt * 16) * RR;
#pragma unroll
  for (int t = 0; t < 4; ++t)
#pragma unroll
    for (int q = 0; q < 4; ++q)
      out[(g * 4 + q) * RR + t * 16 + l15] = f2bfu(acc[t][q]);
}

// ---- reduce 128 bf16 partials -> z bf16 [BATCH][RR] (frozen) --------------
__global__ __launch_bounds__(1024) void k_red(const u16* __restrict__ zp,
                                              u16* __restrict__ zb) {
  __shared__ float part[4][256];
  int il = threadIdx.x & 255;
  int tg = threadIdx.x >> 8;
  int i = blockIdx.x * 256 + il;
  const u16* p = zp + (size_t)tg * 32 * (BATCH * RR) + i;
  float s0 = 0.f, s1 = 0.f, s2 = 0.f, s3 = 0.f;
#pragma unroll
  for (int t = 0; t < 32; t += 4) {
    s0 += bf2f(p[(size_t)(t + 0) * (BATCH * RR)]);
    s1 += bf2f(p[(size_t)(t + 1) * (BATCH * RR)]);
    s2 += bf2f(p[(size_t)(t + 2) * (BATCH * RR)]);
    s3 += bf2f(p[(size_t)(t + 3) * (BATCH * RR)]);
  }
  part[tg][il] = (s0 + s1) + (s2 + s3);
  __syncthreads();
  if (tg == 0)
    zb[i] = f2bfu((part[0][il] + part[1][il]) + (part[2][il] + part[3][il]));
}

// ---- GEMM2 v5: no global load after first store ---------------------------
// Theory: vmcnt counts loads AND stores; any global load issued after stores
// forces s_waitcnt vmcnt(0) that drains the store stream (the 26us stall).
// Structure: stage U->LDS, barrier, ALL {zb loads + LDS reads + MFMA} into
// acc[4][4], then one terminal pure burst of 16 f32x4 stores per thread.
__global__ __launch_bounds__(512, 4) void k2(const u16* __restrict__ zb,
                                             const float* __restrict__ U,
                                             float* __restrict__ y) {
  __shared__ u16 Ub[512 * 64];  // 64 KB, byte = (row*128+col*2)^((row&7)<<4)
  int bid = blockIdx.x;
  int eff = (bid & 7) * 64 + (bid >> 3);  // bijective (512 % 8 == 0)
  int nt = eff >> 3;                      // 8 consecutive n-tiles per XCD
  int bg = eff & 7;
  int n0 = nt * 512;
  int t = threadIdx.x;
  int lane = t & 63;
  int w = t >> 6;                         // 0..7
  int l15 = lane & 15, g = lane >> 4;
  char* Uc = reinterpret_cast<char*>(Ub);

  // stage U slice -> LDS bf16: 32768 floats = 16 iters x 512 thr x 4
#pragma unroll
  for (int i = 0; i < 16; ++i) {
    int f = i * 2048 + t * 4;  // linear float idx within 512x64 slice
    int row = f >> 6;
    int colb = (f & 63) * 2;   // byte col, 8B-aligned
    f32x4 u = *reinterpret_cast<const f32x4*>(U + (size_t)n0 * RR + f);
    uint2 pk;
    pk.x = (u32)f2bfu(u.x) | ((u32)f2bfu(u.y) << 16);
    pk.y = (u32)f2bfu(u.z) | ((u32)f2bfu(u.w) << 16);
    *reinterpret_cast<uint2*>(Uc + ((row * 128 + colb) ^ ((row & 7) << 4))) = pk;
  }
  __syncthreads();

  // compute ALL tiles first (global zb loads all precede any store)
  f32x4 acc[4][4] = {};
#pragma unroll
  for (int it = 0; it < 4; ++it) {
    int b0 = bg * 64 + it * 16;
    const u16* A = zb + (size_t)(b0 + l15) * RR + g * 8;
    bf16x8 z0 = *reinterpret_cast<const bf16x8*>(A);       // k 0..31 slice
    bf16x8 z1 = *reinterpret_cast<const bf16x8*>(A + 32);  // k 32..63 slice
#pragma unroll
    for (int j = 0; j < 4; ++j) {
      int tau = w + 8 * j;               // n-tile 0..31 within block
      int row = tau * 16 + l15;          // U row (n) 0..511
      int base = row * 128;
      int swz = (row & 7) << 4;
      bf16x8 uA = *reinterpret_cast<const bf16x8*>(Uc + ((base + g * 16) ^ swz));
      bf16x8 uB = *reinterpret_cast<const bf16x8*>(Uc + ((base + 64 + g * 16) ^ swz));
      // swapped: A-operand = U rows (D-row space = n), B-operand = z rows
      acc[it][j] = __builtin_amdgcn_mfma_f32_16x16x32_bf16(uA, z0, acc[it][j], 0, 0, 0);
      acc[it][j] = __builtin_amdgcn_mfma_f32_16x16x32_bf16(uB, z1, acc[it][j], 0, 0, 0);
    }
  }

  // terminal pure store burst: 16 f32x4 per thread, no vmem after
#pragma unroll
  for (int it = 0; it < 4; ++it) {
    float* yb = y + (size_t)(bg * 64 + it * 16 + l15) * NPOST + n0;
#pragma unroll
    for (int j = 0; j < 4; ++j) {
      int tau = w + 8 * j;
      *reinterpret_cast<f32x4*>(yb + tau * 16 + g * 4) = acc[it][j];
    }
  }
}

extern "C" void kernel_launch(void* const* d_in, const int* in_sizes, int n_in,
                              void* d_out, int out_size, void* d_ws, size_t ws_size,
                              hipStream_t stream) {
  const float* spikes = (const float*)d_in[0];
  const float* U = (const float*)d_in[1];
  const float* V = (const float*)d_in[2];
  // d_in[3..5]: CSR mask — dead in the reference, unused.
  float* y = (float*)d_out;
  char* ws = (char*)d_ws;
  u16* zp = (u16*)ws;                    // 8 MiB  [KSPLIT][BATCH][RR] bf16
  u16* zb = (u16*)(ws + (8u << 20));     // 64 KiB [BATCH][RR] bf16

  k1<<<1024, 256, 0, stream>>>(spikes, V, zp);
  k_red<<<128, 1024, 0, stream>>>(zp, zb);
  k2<<<512, 512, 0, stream>>>(zb, U, y);
}